// Round 1
// baseline (3516.811 us; speedup 1.0000x reference)
//
#include <hip/hip_runtime.h>
#include <float.h>
#include <math.h>

// Problem constants (HierarchicalMassivePool)
#define BATCH 32
#define TSEQ  1024
#define DIM   512
#define NKEYS 500000
#define MAXK  64
#define NCH   16                       // K3 chunks per row
#define CHUNK (NKEYS / NCH)            // 31250
#define BK    32                       // K2 k-slab
#define KPB   256                      // K2 keys per block

// ws layout in floats
#define WS_SCORES  ((size_t)0)
#define WS_QUERY   (WS_SCORES + (size_t)BATCH * NKEYS)     // 16,000,000
#define WS_PARTIAL (WS_QUERY + BATCH * DIM)                // +16,384
#define WS_CANDV   (WS_PARTIAL + BATCH * 8 * DIM)          // +131,072
#define WS_CANDI   (WS_CANDV + (size_t)BATCH * NCH * MAXK) // +32,768
// total ~16.2M floats = ~65 MB

// ---------------- K1a: partial sums over T ----------------
__global__ __launch_bounds__(256) void k1a_partial_mean(
    const float* __restrict__ hidden, float* __restrict__ partial) {
  int blk = blockIdx.x;            // b*8 + c
  int b = blk >> 3, c = blk & 7;
  int tid = threadIdx.x;
  float s0 = 0.f, s1 = 0.f;
  const float* base = hidden + ((size_t)b * TSEQ + (size_t)c * 128) * DIM;
  for (int t = 0; t < 128; ++t) {
    s0 += base[(size_t)t * DIM + tid];
    s1 += base[(size_t)t * DIM + tid + 256];
  }
  partial[(size_t)blk * DIM + tid] = s0;
  partial[(size_t)blk * DIM + tid + 256] = s1;
}

// ---------------- K1b: pooled -> query = pooled@W + b, pre-scaled 1/sqrt(D) ----------------
__global__ __launch_bounds__(256) void k1b_query(
    const float* __restrict__ partial, const float* __restrict__ W,
    const float* __restrict__ bias, float* __restrict__ query) {
  __shared__ float pl[DIM];
  int b = blockIdx.x, tid = threadIdx.x;
  float s0 = 0.f, s1 = 0.f;
  for (int c = 0; c < 8; ++c) {
    s0 += partial[(size_t)(b * 8 + c) * DIM + tid];
    s1 += partial[(size_t)(b * 8 + c) * DIM + tid + 256];
  }
  pl[tid]       = s0 * (1.0f / 1024.0f);
  pl[tid + 256] = s1 * (1.0f / 1024.0f);
  __syncthreads();
  float q0 = bias[tid], q1 = bias[tid + 256];
  for (int k = 0; k < DIM; ++k) {
    float pk = pl[k];
    q0 = fmaf(pk, W[(size_t)k * DIM + tid], q0);
    q1 = fmaf(pk, W[(size_t)k * DIM + tid + 256], q1);
  }
  const float rsc = 0.044194173824159216f;  // 1/sqrt(512); uniform scale, order-preserving
  query[(size_t)b * DIM + tid]       = q0 * rsc;
  query[(size_t)b * DIM + tid + 256] = q1 * rsc;
}

// ---------------- K2: scores[m][n] = q'[m] . key[n]  (1 key/thread, 32 accs) ----------------
__global__ __launch_bounds__(256) void k2_scores(
    const float* __restrict__ query, const float* __restrict__ keys,
    float* __restrict__ scores) {
  __shared__ float klds[KPB * 36];   // 256 keys x BK floats, row stride 36 (conflict-free)
  __shared__ float qlds[32 * BK];    // 32 queries x BK floats
  int tid = threadIdx.x;
  int n0 = blockIdx.x * KPB;
  int n = n0 + tid;
  float acc[32];
#pragma unroll
  for (int m = 0; m < 32; ++m) acc[m] = 0.f;

  for (int ks = 0; ks < DIM; ks += BK) {
    __syncthreads();
    // stage keys slab: 256 rows x 32 floats = 2048 float4 chunks, 8 per thread
#pragma unroll
    for (int i = 0; i < 8; ++i) {
      int id = i * 256 + tid;
      int row = id >> 3;
      int c4 = (id & 7) << 2;
      int gr = n0 + row; if (gr >= NKEYS) gr = NKEYS - 1;   // clamp; masked at write
      float4 v = *(const float4*)(keys + (size_t)gr * DIM + ks + c4);
      *(float4*)(&klds[row * 36 + c4]) = v;
    }
    // stage query slab: 32 rows x 32 floats = 256 float4 chunks, 1 per thread
    {
      int row = tid >> 3;
      int c4 = (tid & 7) << 2;
      float4 v = *(const float4*)(query + (size_t)row * DIM + ks + c4);
      *(float4*)(&qlds[row * BK + c4]) = v;
    }
    __syncthreads();
#pragma unroll
    for (int kk = 0; kk < BK; kk += 4) {
      float4 kv = *(const float4*)(&klds[tid * 36 + kk]);
#pragma unroll
      for (int m = 0; m < 32; ++m) {
        float4 qv = *(const float4*)(&qlds[m * BK + kk]);
        acc[m] += qv.x * kv.x + qv.y * kv.y + qv.z * kv.z + qv.w * kv.w;
      }
    }
  }
  if (n < NKEYS) {
#pragma unroll
    for (int m = 0; m < 32; ++m) scores[(size_t)m * NKEYS + n] = acc[m];
  }
}

// ---------------- wave-wide exact top-64: register buffer + ballot insert ----------------
// buffer entry per lane: (rv, ri). (tau,tau_i,tau_slot) = current weakest (wave-uniform).
// ordering: better = (v larger) or (v equal and idx smaller)  [matches lax.top_k stability]
__device__ __forceinline__ void topk_scan_insert(
    float v, int idx, int lane,
    float& rv, int& ri, float& tau, int& tau_i, int& tau_slot) {
  bool pred = (v > tau) || (v == tau && idx < tau_i);
  unsigned long long mask = __ballot(pred);
  while (mask) {
    int src = __ffsll(mask) - 1;
    mask &= mask - 1;
    float bv = __shfl(v, src);
    int   bi = __shfl(idx, src);
    if ((bv > tau) || (bv == tau && bi < tau_i)) {    // re-check vs current tau
      if (lane == tau_slot) { rv = bv; ri = bi; }
      // recompute weakest entry (min by value, tie -> larger idx, tie -> larger slot)
      float mv = rv; int mi = ri; int ms = lane;
#pragma unroll
      for (int off = 1; off < 64; off <<= 1) {
        float ov = __shfl_xor(mv, off);
        int   oi = __shfl_xor(mi, off);
        int   os = __shfl_xor(ms, off);
        bool worse = (ov < mv) || (ov == mv && (oi > mi || (oi == mi && os > ms)));
        if (worse) { mv = ov; mi = oi; ms = os; }
      }
      tau = mv; tau_i = mi; tau_slot = ms;
    }
  }
}

// ---------------- K3: per (row, chunk) top-64 -> candidates ----------------
__global__ __launch_bounds__(64) void k3_topk_chunk(
    const float* __restrict__ scores, float* __restrict__ cand_v,
    int* __restrict__ cand_i) {
  int blk = blockIdx.x;           // r * NCH + c
  int r = blk / NCH, c = blk % NCH;
  int lane = threadIdx.x;
  int base = c * CHUNK;
  int lim = base + CHUNK;
  const float* srow = scores + (size_t)r * NKEYS;

  float rv = -FLT_MAX; int ri = 0x7FFFFFFF;
  float tau = -FLT_MAX; int tau_i = 0x7FFFFFFF; int tau_slot = 0;

  int iters = (CHUNK + 63) / 64;
  for (int it = 0; it < iters; ++it) {
    int p = base + it * 64 + lane;
    float v = -FLT_MAX; int idx = 0x7FFFFFFF;
    if (p < lim) { v = srow[p]; idx = p; }
    topk_scan_insert(v, idx, lane, rv, ri, tau, tau_i, tau_slot);
  }
  cand_v[(size_t)blk * 64 + lane] = rv;
  cand_i[(size_t)blk * 64 + lane] = ri;
}

// ---------------- K4: merge candidates, softmax(top-k_dyn), gather + weighted sum ----------------
__global__ __launch_bounds__(256) void k4_final(
    const float* __restrict__ cand_v, const int* __restrict__ cand_i,
    const float* __restrict__ params, const int* __restrict__ kdyn_p,
    const int* __restrict__ maxk_p, float* __restrict__ out) {
  __shared__ float w_sh[64];
  __shared__ int   i_sh[64];
  __shared__ int   kk_sh;
  int r = blockIdx.x, tid = threadIdx.x;

  if (tid < 64) {
    int lane = tid;
    float rv = -FLT_MAX; int ri = 0x7FFFFFFF;
    float tau = -FLT_MAX; int tau_i = 0x7FFFFFFF; int tau_slot = 0;
    // merge NCH*64 candidates
    for (int it = 0; it < NCH; ++it) {
      float v = cand_v[(size_t)r * (NCH * 64) + it * 64 + lane];
      int  idx = cand_i[(size_t)r * (NCH * 64) + it * 64 + lane];
      topk_scan_insert(v, idx, lane, rv, ri, tau, tau_i, tau_slot);
    }
    int kd = kdyn_p[0];
    int mk = maxk_p[0]; if (mk > MAXK) mk = MAXK; if (mk < 1) mk = 1;
    int kk = kd;
    if (kk > mk) kk = mk;
    bool uniform = (kk <= 0);        // all masked -> softmax over mk equal values
    if (uniform) kk = mk;

    // extract top-kk in order (max first). lane j keeps selection j in registers.
    float sel_v = -FLT_MAX; int sel_i = 0;
    float maxv = 0.f;
    for (int j = 0; j < kk; ++j) {
      float mv = rv; int mi = ri; int ms = lane;
#pragma unroll
      for (int off = 1; off < 64; off <<= 1) {
        float ov = __shfl_xor(mv, off);
        int   oi = __shfl_xor(mi, off);
        int   os = __shfl_xor(ms, off);
        bool better = (ov > mv) || (ov == mv && (oi < mi || (oi == mi && os < ms)));
        if (better) { mv = ov; mi = oi; ms = os; }
      }
      if (j == 0) maxv = mv;
      if (lane == j)  { sel_v = mv; sel_i = mi; }
      if (lane == ms) { rv = -FLT_MAX; ri = 0x7FFFFFFF; }   // evict
    }
    // softmax over lanes [0, kk)
    float e = 0.f;
    if (lane < kk) e = uniform ? 1.0f : expf(sel_v - maxv);
    float ssum = e;
#pragma unroll
    for (int off = 1; off < 64; off <<= 1) ssum += __shfl_xor(ssum, off);
    float w = (lane < kk) ? (e / ssum) : 0.0f;
    w_sh[lane] = w;
    i_sh[lane] = sel_i;
    if (lane == 0) kk_sh = kk;
  }
  __syncthreads();

  int kk = kk_sh;
  float a0 = 0.f, a1 = 0.f;
  for (int j = 0; j < kk; ++j) {
    float w = w_sh[j];
    const float* pr = params + (size_t)i_sh[j] * DIM;
    a0 = fmaf(w, pr[tid], a0);
    a1 = fmaf(w, pr[tid + 256], a1);
  }
  out[(size_t)r * DIM + tid]       = a0;
  out[(size_t)r * DIM + tid + 256] = a1;
}

// ---------------- launch ----------------
extern "C" void kernel_launch(void* const* d_in, const int* in_sizes, int n_in,
                              void* d_out, int out_size, void* d_ws, size_t ws_size,
                              hipStream_t stream) {
  const float* hidden = (const float*)d_in[0];
  const float* params = (const float*)d_in[1];
  const float* keys   = (const float*)d_in[2];
  const float* W      = (const float*)d_in[3];
  const float* bias   = (const float*)d_in[4];
  const int*   kdyn   = (const int*)d_in[5];
  const int*   maxk   = (const int*)d_in[6];
  float* out = (float*)d_out;
  float* ws  = (float*)d_ws;

  float* scores  = ws + WS_SCORES;
  float* query   = ws + WS_QUERY;
  float* partial = ws + WS_PARTIAL;
  float* cand_v  = ws + WS_CANDV;
  int*   cand_i  = (int*)(ws + WS_CANDI);

  hipLaunchKernelGGL(k1a_partial_mean, dim3(BATCH * 8), dim3(256), 0, stream,
                     hidden, partial);
  hipLaunchKernelGGL(k1b_query, dim3(BATCH), dim3(256), 0, stream,
                     partial, W, bias, query);
  hipLaunchKernelGGL(k2_scores, dim3((NKEYS + KPB - 1) / KPB), dim3(256), 0, stream,
                     query, keys, scores);
  hipLaunchKernelGGL(k3_topk_chunk, dim3(BATCH * NCH), dim3(64), 0, stream,
                     scores, cand_v, cand_i);
  hipLaunchKernelGGL(k4_final, dim3(BATCH), dim3(256), 0, stream,
                     cand_v, cand_i, params, kdyn, maxk, out);
}